// Round 1
// baseline (230.423 us; speedup 1.0000x reference)
//
#include <hip/hip_runtime.h>
#include <math.h>

#define B_SEQ 65536
#define T_SEQ 34
#define VOCAB 14
#define NTOK (B_SEQ * T_SEQ)   // 2228224 = 8704 * 256 exactly
#define NBLK 8704

__device__ __forceinline__ void layernorm6(const float* x, const float* g,
                                           const float* bt, float* o) {
    float mu = (x[0] + x[1] + x[2] + x[3] + x[4] + x[5]) * (1.0f / 6.0f);
    float var = 0.0f;
#pragma unroll
    for (int i = 0; i < 6; ++i) { float d = x[i] - mu; var += d * d; }
    var *= (1.0f / 6.0f);
    float rs = rsqrtf(var + 1e-5f);
#pragma unroll
    for (int i = 0; i < 6; ++i) o[i] = (x[i] - mu) * rs * g[i] + bt[i];
}

__global__ __launch_bounds__(256) void fused_tf_kernel(
    const int* __restrict__ idx,
    const float* __restrict__ tok_emb,
    const float* __restrict__ pos_enc,
    const float* __restrict__ wq,
    const float* __restrict__ wk,
    const float* __restrict__ wv,
    const float* __restrict__ wo,
    const float* __restrict__ ln1_g, const float* __restrict__ ln1_b,
    const float* __restrict__ ln2_g, const float* __restrict__ ln2_b,
    const float* __restrict__ w1,   const float* __restrict__ b1,
    const float* __restrict__ w2,   const float* __restrict__ b2,
    const float* __restrict__ lnf_g, const float* __restrict__ lnf_b,
    const float* __restrict__ w_head,
    float* __restrict__ out)
{
    // kv table: [t][vocab][12] = k(h0:3,h1:3), v(h0:3,h1:3). 34*14*12*4 = 22.8 KB
    __shared__ float kvtab[T_SEQ * VOCAB * 12];

    const int tid = threadIdx.x;

    // ---- build (tok,t) -> (k,v) table: only 476 distinct token states ----
    for (int e = tid; e < T_SEQ * VOCAB; e += 256) {
        const int t = e / VOCAB;
        const int v = e - t * VOCAB;
        float x[6];
#pragma unroll
        for (int i = 0; i < 3; ++i) x[i] = tok_emb[v * 3 + i];
#pragma unroll
        for (int i = 0; i < 3; ++i) x[3 + i] = pos_enc[t * 3 + i];
        float xl[6];
        layernorm6(x, ln1_g, ln1_b, xl);
        float* dst = &kvtab[e * 12];
#pragma unroll
        for (int j = 0; j < 6; ++j) {
            dst[j]     = xl[3] * wk[j] + xl[4] * wk[6 + j] + xl[5] * wk[12 + j];
            dst[6 + j] = xl[0] * wv[j] + xl[1] * wv[6 + j] + xl[2] * wv[12 + j];
        }
    }
    __syncthreads();

    const int g = blockIdx.x * 256 + tid;          // grid sized exactly: no bounds check
    const unsigned b = (unsigned)g / (unsigned)T_SEQ;  // magic-mul division
    const int t = g - (int)b * T_SEQ;

    // ---- own token state + q ----
    const int mytok = idx[g];
    float x[6];
#pragma unroll
    for (int i = 0; i < 3; ++i) x[i] = tok_emb[mytok * 3 + i];
#pragma unroll
    for (int i = 0; i < 3; ++i) x[3 + i] = pos_enc[t * 3 + i];
    float xl[6];
    layernorm6(x, ln1_g, ln1_b, xl);
    float q[6];
    const float scale = 0.57735026918962576f;  // 1/sqrt(HEAD_DIM)
#pragma unroll
    for (int j = 0; j < 6; ++j)
        q[j] = (xl[3] * wq[j] + xl[4] * wq[6 + j] + xl[5] * wq[12 + j]) * scale;

    // ---- causal attention over prefix; scores bounded -> no max-subtract ----
    float den0 = 0.0f, den1 = 0.0f;
    float acc[6] = {0.f, 0.f, 0.f, 0.f, 0.f, 0.f};
    const int base = (int)b * T_SEQ;
    for (int s = 0; s <= t; ++s) {
        const int tk = idx[base + s];
        const float* e = &kvtab[(s * VOCAB + tk) * 12];
        const float s0 = q[0] * e[0] + q[1] * e[1] + q[2] * e[2];
        const float s1 = q[3] * e[3] + q[4] * e[4] + q[5] * e[5];
        const float p0 = __expf(s0);
        const float p1 = __expf(s1);
        den0 += p0; den1 += p1;
        acc[0] += p0 * e[6];  acc[1] += p0 * e[7];  acc[2] += p0 * e[8];
        acc[3] += p1 * e[9];  acc[4] += p1 * e[10]; acc[5] += p1 * e[11];
    }
    const float inv0 = 1.0f / den0;
    const float inv1 = 1.0f / den1;
    float ao[6];
#pragma unroll
    for (int i = 0; i < 3; ++i) { ao[i] = acc[i] * inv0; ao[3 + i] = acc[3 + i] * inv1; }

    // ---- attn out proj + residual ----
    float x2[6];
#pragma unroll
    for (int j = 0; j < 6; ++j) {
        float s = x[j];
#pragma unroll
        for (int i = 0; i < 6; ++i) s += ao[i] * wo[i * 6 + j];
        x2[j] = s;
    }

    // ---- FFN ----
    float h[6];
    layernorm6(x2, ln2_g, ln2_b, h);
    float f[6];
#pragma unroll
    for (int j = 0; j < 6; ++j) {
        float s = b1[j];
#pragma unroll
        for (int i = 0; i < 6; ++i) s += h[i] * w1[i * 6 + j];
        // exact GELU: 0.5*x*(1+erf(x/sqrt(2)))
        f[j] = 0.5f * s * (1.0f + erff(s * 0.70710678118654752f));
    }
    float x3[6];
#pragma unroll
    for (int j = 0; j < 6; ++j) {
        float s = x2[j] + b2[j];
#pragma unroll
        for (int i = 0; i < 6; ++i) s += f[i] * w2[i * 6 + j];
        x3[j] = s;
    }

    // ---- final LN + head ----
    float xo[6];
    layernorm6(x3, lnf_g, lnf_b, xo);
    float o[14];
#pragma unroll
    for (int j = 0; j < 14; ++j) {
        float s = 0.0f;
#pragma unroll
        for (int i = 0; i < 6; ++i) s += xo[i] * w_head[i * 14 + j];
        o[j] = s;
    }

    // coalesced-ish write: 56 contiguous bytes per lane, contiguous across wave
    float2* op = (float2*)(out + (size_t)g * 14);
#pragma unroll
    for (int j = 0; j < 7; ++j) op[j] = make_float2(o[2 * j], o[2 * j + 1]);
}

extern "C" void kernel_launch(void* const* d_in, const int* in_sizes, int n_in,
                              void* d_out, int out_size, void* d_ws, size_t ws_size,
                              hipStream_t stream) {
    const int*   idx     = (const int*)d_in[0];
    const float* tok_emb = (const float*)d_in[1];
    const float* pos_enc = (const float*)d_in[2];
    const float* wq      = (const float*)d_in[3];
    const float* wk      = (const float*)d_in[4];
    const float* wv      = (const float*)d_in[5];
    const float* wo      = (const float*)d_in[6];
    const float* ln1_g   = (const float*)d_in[7];
    const float* ln1_b   = (const float*)d_in[8];
    const float* ln2_g   = (const float*)d_in[9];
    const float* ln2_b   = (const float*)d_in[10];
    const float* w1      = (const float*)d_in[11];
    const float* b1      = (const float*)d_in[12];
    const float* w2      = (const float*)d_in[13];
    const float* b2      = (const float*)d_in[14];
    const float* lnf_g   = (const float*)d_in[15];
    const float* lnf_b   = (const float*)d_in[16];
    const float* w_head  = (const float*)d_in[17];
    float* out = (float*)d_out;

    hipLaunchKernelGGL(fused_tf_kernel, dim3(NBLK), dim3(256), 0, stream,
                       idx, tok_emb, pos_enc, wq, wk, wv, wo,
                       ln1_g, ln1_b, ln2_g, ln2_b, w1, b1, w2, b2,
                       lnf_g, lnf_b, w_head, out);
}

// Round 2
// 225.939 us; speedup vs baseline: 1.0198x; 1.0198x over previous
//
#include <hip/hip_runtime.h>
#include <math.h>

#define B_SEQ 65536
#define T_SEQ 34
#define VOCAB 14
#define SEQS_PER_BLK 16
#define ACTIVE (SEQS_PER_BLK * T_SEQ)   // 544
#define BLK_THREADS 576                  // 9 full waves; tid 544..575 idle after sync
#define NBLK (B_SEQ / SEQS_PER_BLK)      // 4096

__device__ __forceinline__ void layernorm6(const float* x, const float* g,
                                           const float* bt, float* o) {
    float mu = (x[0] + x[1] + x[2] + x[3] + x[4] + x[5]) * (1.0f / 6.0f);
    float var = 0.0f;
#pragma unroll
    for (int i = 0; i < 6; ++i) { float d = x[i] - mu; var += d * d; }
    var *= (1.0f / 6.0f);
    float rs = rsqrtf(var + 1e-5f);
#pragma unroll
    for (int i = 0; i < 6; ++i) o[i] = (x[i] - mu) * rs * g[i] + bt[i];
}

__global__ __launch_bounds__(BLK_THREADS) void fused_tf_kernel(
    const int* __restrict__ idx,
    const float* __restrict__ tok_emb,
    const float* __restrict__ pos_enc,
    const float* __restrict__ wq,
    const float* __restrict__ wk,
    const float* __restrict__ wv,
    const float* __restrict__ wo,
    const float* __restrict__ ln1_g, const float* __restrict__ ln1_b,
    const float* __restrict__ ln2_g, const float* __restrict__ ln2_b,
    const float* __restrict__ w1,   const float* __restrict__ b1,
    const float* __restrict__ w2,   const float* __restrict__ b2,
    const float* __restrict__ lnf_g, const float* __restrict__ lnf_b,
    const float* __restrict__ w_head,
    float* __restrict__ out)
{
    // kv table: [t][vocab][12] = k(h0:3,h1:3), v(h0:3,h1:3). stride 48 B, 16-B aligned.
    __shared__ __align__(16) float kvtab[T_SEQ * VOCAB * 12];  // 22.8 KB
    __shared__ int idx_lds[ACTIVE];                             // 2.2 KB

    const int tid = threadIdx.x;

    // ---- build (t,tok) -> (k,v) table: 476 distinct token states ----
    if (tid < T_SEQ * VOCAB) {
        const int e = tid;
        const int t = e / VOCAB;
        const int v = e - t * VOCAB;
        float x[6];
#pragma unroll
        for (int i = 0; i < 3; ++i) x[i] = tok_emb[v * 3 + i];
#pragma unroll
        for (int i = 0; i < 3; ++i) x[3 + i] = pos_enc[t * 3 + i];
        float xl[6];
        layernorm6(x, ln1_g, ln1_b, xl);
        float* dst = &kvtab[e * 12];
#pragma unroll
        for (int j = 0; j < 6; ++j) {
            dst[j]     = xl[3] * wk[j] + xl[4] * wk[6 + j] + xl[5] * wk[12 + j];
            dst[6 + j] = xl[0] * wv[j] + xl[1] * wv[6 + j] + xl[2] * wv[12 + j];
        }
    }
    // ---- stage this block's 16 sequences of idx (544 ints, coalesced) ----
    if (tid < ACTIVE) idx_lds[tid] = idx[blockIdx.x * ACTIVE + tid];
    __syncthreads();

    if (tid >= ACTIVE) return;   // no further barriers

    // lane map: 16 seqs x 4 consecutive t per wave; descending t so the
    // half-idle 9th wave gets the shortest loops.
    const int seq = tid & 15;
    const int t   = 33 - (tid >> 4);
    const int b   = blockIdx.x * SEQS_PER_BLK + seq;
    const int g   = b * T_SEQ + t;
    const int* myidx = &idx_lds[seq * T_SEQ];

    // ---- own token state + q ----
    const int mytok = myidx[t];
    float x[6];
#pragma unroll
    for (int i = 0; i < 3; ++i) x[i] = tok_emb[mytok * 3 + i];
#pragma unroll
    for (int i = 0; i < 3; ++i) x[3 + i] = pos_enc[t * 3 + i];
    float xl[6];
    layernorm6(x, ln1_g, ln1_b, xl);
    float q[6];
    const float scale = 0.57735026918962576f;  // 1/sqrt(HEAD_DIM)
#pragma unroll
    for (int j = 0; j < 6; ++j)
        q[j] = (xl[3] * wq[j] + xl[4] * wq[6 + j] + xl[5] * wq[12 + j]) * scale;

    // ---- causal attention; scores bounded -> no max-subtract ----
    float den0 = 0.0f, den1 = 0.0f;
    float acc[6] = {0.f, 0.f, 0.f, 0.f, 0.f, 0.f};
    for (int s = 0; s <= t; ++s) {
        const int tk = myidx[s];                       // LDS broadcast (4 lanes/seq)
        const float4* e4 = (const float4*)&kvtab[(s * VOCAB + tk) * 12];
        const float4 ea = e4[0];   // k0.x k0.y k0.z k1.x
        const float4 eb = e4[1];   // k1.y k1.z v0.x v0.y
        const float4 ec = e4[2];   // v0.z v1.x v1.y v1.z
        const float s0 = q[0] * ea.x + q[1] * ea.y + q[2] * ea.z;
        const float s1 = q[3] * ea.w + q[4] * eb.x + q[5] * eb.y;
        const float p0 = __expf(s0);
        const float p1 = __expf(s1);
        den0 += p0; den1 += p1;
        acc[0] += p0 * eb.z;  acc[1] += p0 * eb.w;  acc[2] += p0 * ec.x;
        acc[3] += p1 * ec.y;  acc[4] += p1 * ec.z;  acc[5] += p1 * ec.w;
    }
    const float inv0 = 1.0f / den0;
    const float inv1 = 1.0f / den1;
    float ao[6];
#pragma unroll
    for (int i = 0; i < 3; ++i) { ao[i] = acc[i] * inv0; ao[3 + i] = acc[3 + i] * inv1; }

    // ---- attn out proj + residual ----
    float x2[6];
#pragma unroll
    for (int j = 0; j < 6; ++j) {
        float s = x[j];
#pragma unroll
        for (int i = 0; i < 6; ++i) s += ao[i] * wo[i * 6 + j];
        x2[j] = s;
    }

    // ---- FFN ----
    float h[6];
    layernorm6(x2, ln2_g, ln2_b, h);
    float f[6];
#pragma unroll
    for (int j = 0; j < 6; ++j) {
        float s = b1[j];
#pragma unroll
        for (int i = 0; i < 6; ++i) s += h[i] * w1[i * 6 + j];
        f[j] = 0.5f * s * (1.0f + erff(s * 0.70710678118654752f));
    }
    float x3[6];
#pragma unroll
    for (int j = 0; j < 6; ++j) {
        float s = x2[j] + b2[j];
#pragma unroll
        for (int i = 0; i < 6; ++i) s += f[i] * w2[i * 6 + j];
        x3[j] = s;
    }

    // ---- final LN + head ----
    float xo[6];
    layernorm6(x3, lnf_g, lnf_b, xo);
    float o[14];
#pragma unroll
    for (int j = 0; j < 14; ++j) {
        float s = 0.0f;
#pragma unroll
        for (int i = 0; i < 6; ++i) s += xo[i] * w_head[i * 14 + j];
        o[j] = s;
    }

    // per-wave: 16 clusters of 4 rows x 56 B = 224 contiguous B each.
    // whole block covers a contiguous 16*1904 B region -> L2 merges lines.
    float2* op = (float2*)(out + (size_t)g * 14);
#pragma unroll
    for (int j = 0; j < 7; ++j) op[j] = make_float2(o[2 * j], o[2 * j + 1]);
}

extern "C" void kernel_launch(void* const* d_in, const int* in_sizes, int n_in,
                              void* d_out, int out_size, void* d_ws, size_t ws_size,
                              hipStream_t stream) {
    const int*   idx     = (const int*)d_in[0];
    const float* tok_emb = (const float*)d_in[1];
    const float* pos_enc = (const float*)d_in[2];
    const float* wq      = (const float*)d_in[3];
    const float* wk      = (const float*)d_in[4];
    const float* wv      = (const float*)d_in[5];
    const float* wo      = (const float*)d_in[6];
    const float* ln1_g   = (const float*)d_in[7];
    const float* ln1_b   = (const float*)d_in[8];
    const float* ln2_g   = (const float*)d_in[9];
    const float* ln2_b   = (const float*)d_in[10];
    const float* w1      = (const float*)d_in[11];
    const float* b1      = (const float*)d_in[12];
    const float* w2      = (const float*)d_in[13];
    const float* b2      = (const float*)d_in[14];
    const float* lnf_g   = (const float*)d_in[15];
    const float* lnf_b   = (const float*)d_in[16];
    const float* w_head  = (const float*)d_in[17];
    float* out = (float*)d_out;

    hipLaunchKernelGGL(fused_tf_kernel, dim3(NBLK), dim3(BLK_THREADS), 0, stream,
                       idx, tok_emb, pos_enc, wq, wk, wv, wo,
                       ln1_g, ln1_b, ln2_g, ln2_b, w1, b1, w2, b2,
                       lnf_g, lnf_b, w_head, out);
}